// Round 16
// baseline (213.401 us; speedup 1.0000x reference)
//
#include <hip/hip_runtime.h>

#define EPSF 1e-5f
#define TOTBINS 1146880   // 70*16*1024

typedef _Float16 v8h __attribute__((ext_vector_type(8)));
typedef _Float16 v4h __attribute__((ext_vector_type(4)));
typedef float v4f __attribute__((ext_vector_type(4)));

// ---- workspace offsets (in float slots) ----
#define OFF_PARTX   1146880
#define OFF_W1F     1149952
#define OFF_B1F     1150144
#define OFF_PMU1    1150208
#define OFF_M1N     1166592
#define OFF_MU1     1170688
#define OFF_W2H     1170752
#define OFF_W2L     1174848
#define OFF_B2F     1178944
#define OFF_PMU2    1179072
#define OFF_M2N     1211840
#define OFF_MU2     1228224
#define OFF_W3H     1228352   // 1024x128 f16 = 65536 float slots
#define OFF_W3L     1293888
#define OFF_B3F     1359424
#define OFF_H1H     1360448   // 16*4096*64 f16 = 2097152 float slots
#define OFF_H1L     3457600
#define OFF_H2H     5554752   // 16*4096*128 f16 = 4194304 float slots
#define OFF_H2L     9749056   // ends 13943360 (55.8 MB)

#define GLL(src,dst) __builtin_amdgcn_global_load_lds( \
    (const __attribute__((address_space(1))) void*)(src), \
    (__attribute__((address_space(3))) void*)(dst), 16, 0, 0)

// ---------- stats of x ----------
__global__ void k_statsX(const float* __restrict__ x, float* __restrict__ part){
  __shared__ float red[12][256];
  int t = threadIdx.x;
  int s = blockIdx.x*256 + t;
  int b = s >> 12, n = s & 4095;
  const float* xb = x + (size_t)b*12288 + n;
  float x0 = xb[0], x1 = xb[4096], x2 = xb[8192];
  float v[12] = {x0,x1,x2, x0*x0,x0*x1,x0*x2, x1*x1,x1*x2,x2*x2, 0.f,0.f,0.f};
  #pragma unroll
  for(int j=0;j<12;j++) red[j][t]=v[j];
  __syncthreads();
  for(int off=128; off>0; off>>=1){
    if(t<off){
      #pragma unroll
      for(int j=0;j<12;j++) red[j][t]+=red[j][t+off];
    }
    __syncthreads();
  }
  if(t<12) part[blockIdx.x*12+t]=red[t][0];
}

__global__ void k_fold1(const float* __restrict__ part,
                        const float* __restrict__ w1, const float* __restrict__ b1,
                        const float* __restrict__ g1, const float* __restrict__ be1,
                        float* __restrict__ W1f, float* __restrict__ B1f){
  __shared__ double S[12];
  int t=threadIdx.x;
  if(t<12){
    double a=0.0;
    for(int s=0;s<256;s++) a+=(double)part[s*12+t];
    S[t]=a;
  }
  __syncthreads();
  if(t<64){
    double inv = 1.0/65536.0;
    double mu[3]={S[0]*inv,S[1]*inv,S[2]*inv};
    double M[3][3];
    M[0][0]=S[3]*inv; M[0][1]=S[4]*inv; M[0][2]=S[5]*inv;
    M[1][1]=S[6]*inv; M[1][2]=S[7]*inv; M[2][2]=S[8]*inv;
    M[1][0]=M[0][1]; M[2][0]=M[0][2]; M[2][1]=M[1][2];
    double w[3]={(double)w1[t*3],(double)w1[t*3+1],(double)w1[t*3+2]};
    double wm=0.0, q=0.0;
    for(int c=0;c<3;c++){
      wm += w[c]*mu[c];
      for(int d=0;d<3;d++) q += w[c]*w[d]*M[c][d];
    }
    double var = q - wm*wm;
    double m = wm + (double)b1[t];
    double sc = (double)g1[t] / sqrt(var + (double)EPSF);
    for(int c=0;c<3;c++) W1f[t*3+c]=(float)(w[c]*sc);
    B1f[t]=(float)(((double)b1[t]-m)*sc + (double)be1[t]);
  }
}

// ---------- fused layer1 + stats1; n-split: 512 WGs x 128 n ----------
__global__ void k_l1s1(const float* __restrict__ x, const float* __restrict__ W1f,
                       const float* __restrict__ B1f,
                       _Float16* __restrict__ h1h, _Float16* __restrict__ h1l,
                       float* __restrict__ partM, float* __restrict__ partMu){
  __shared__ __align__(16) float tl[64][68];
  __shared__ float Wls[192];
  __shared__ float Bls[64];
  int t=threadIdx.x, wg=blockIdx.x;
  int s0=wg*128;
  int b=s0>>12, n0=s0&4095;
  int ti=t&15, tj=t>>4;
  if(t<192) Wls[t]=W1f[t];
  if(t<64)  Bls[t]=B1f[t];
  float acc[4][4];
  #pragma unroll
  for(int i=0;i<4;i++){
    #pragma unroll
    for(int j=0;j<4;j++) acc[i][j]=0.f;
  }
  float mu=0.f;
  for(int tile=0; tile<2; tile++){
    int nb=n0+tile*64;
    __syncthreads();
    {
      int nr=t>>2, cq=(t&3)<<4;
      int n=nb+nr;
      const float* xb = x + (size_t)b*12288 + n;
      float x0=xb[0], x1=xb[4096], x2=xb[8192];
      size_t off = ((size_t)((b<<12)+n))<<6;
      #pragma unroll
      for(int q=0;q<2;q++){
        v8h vh, vl;
        float4 r0, r1;
        #pragma unroll
        for(int e=0;e<8;e++){
          int f=cq+q*8+e;
          float v = fmaf(Wls[f*3+2],x2, fmaf(Wls[f*3+1],x1, fmaf(Wls[f*3],x0, Bls[f])));
          v = v>0.f ? v : 0.f;
          _Float16 hh=(_Float16)v;
          _Float16 ll=(_Float16)(v-(float)hh);
          vh[e]=hh; vl[e]=ll;
          float rec=(float)hh+(float)ll;
          if(e<4) ((float*)&r0)[e]=rec; else ((float*)&r1)[e-4]=rec;
        }
        *(v8h*)(h1h+off+cq+q*8)=vh;
        *(v8h*)(h1l+off+cq+q*8)=vl;
        *(float4*)&tl[nr][cq+q*8]   = r0;
        *(float4*)&tl[nr][cq+q*8+4] = r1;
      }
    }
    __syncthreads();
    for(int k=0;k<64;k++){
      float4 av = *(const float4*)&tl[k][ti*4];
      float4 bv = *(const float4*)&tl[k][tj*4];
      float a[4]={av.x,av.y,av.z,av.w};
      float bb[4]={bv.x,bv.y,bv.z,bv.w};
      #pragma unroll
      for(int i=0;i<4;i++){
        #pragma unroll
        for(int j=0;j<4;j++) acc[i][j]=fmaf(a[i],bb[j],acc[i][j]);
      }
    }
    if(t<64){
      float ss=0.f;
      for(int k=0;k<64;k++) ss+=tl[k][t];
      mu+=ss;
    }
  }
  #pragma unroll
  for(int i=0;i<4;i++){
    #pragma unroll
    for(int j=0;j<4;j++)
      partM[(size_t)wg*4096+(ti*4+i)*64+(tj*4+j)]=acc[i][j];
  }
  if(t<64) partMu[wg*64+t]=mu;
}

__global__ void k_reduceM1(const float* __restrict__ partM, const float* __restrict__ partMu,
                           float* __restrict__ M1n, float* __restrict__ mu1){
  int e=blockIdx.x*256+threadIdx.x;
  double a=0.0;
  for(int s=0;s<512;s++) a+=(double)partM[(size_t)s*4096+e];
  M1n[e]=(float)(a/65536.0);
  if(e<64){
    double m=0.0;
    for(int s=0;s<512;s++) m+=(double)partMu[s*64+e];
    mu1[e]=(float)(m/65536.0);
  }
}

// ---------- fold layer2: f16 hi/lo weight planes ----------
__global__ void k_fold2(const float* __restrict__ w2, const float* __restrict__ b2,
                        const float* __restrict__ g2, const float* __restrict__ be2,
                        const float* __restrict__ M1n, const float* __restrict__ mu1,
                        _Float16* __restrict__ w2h, _Float16* __restrict__ w2l,
                        float* __restrict__ B2f){
  int f=blockIdx.x, t=threadIdx.x;   // block=64
  __shared__ float w[64];
  w[t]=w2[f*64+t];
  __syncthreads();
  double tm=0.0;
  for(int c=0;c<64;c++) tm += (double)w[c]*(double)M1n[c*64+t];
  double pv=tm*(double)w[t];
  double pm=(double)w[t]*(double)mu1[t];
  #pragma unroll
  for(int off=32;off>0;off>>=1){
    pv+=__shfl_xor(pv,off,64);
    pm+=__shfl_xor(pm,off,64);
  }
  double var=pv-pm*pm;
  double m=pm+(double)b2[f];
  double sc=(double)g2[f]/sqrt(var+(double)EPSF);
  float Wf=(float)((double)w[t]*sc);
  _Float16 hh=(_Float16)Wf;
  w2h[f*64+t]=hh;
  w2l[f*64+t]=(_Float16)(Wf-(float)hh);
  if(t==0) B2f[f]=(float)(((double)b2[f]-m)*sc+(double)be2[f]);
}

// ---------- layer2 MFMA GEMM: 128f x 128n per WG, 32n per stage round (gemm3 shape) ----------
// grid 512 = 16b x 32 nslice(128n); 4 waves x 32f; 4 rounds of 32n, dbuf, 1 barrier/round.
__global__ __launch_bounds__(256,4) void k_layer2(
    const _Float16* __restrict__ h1h, const _Float16* __restrict__ h1l,
    const _Float16* __restrict__ w2h, const _Float16* __restrict__ w2l,
    const float* __restrict__ B2f,
    _Float16* __restrict__ h2h, _Float16* __restrict__ h2l){
  __shared__ __align__(16) _Float16 stage[2][8][512];  // [buf][ng*4+ks*2+pln][slot*8]
  int t=threadIdx.x, wg=blockIdx.x;
  int wv=t>>6, l=t&63;
  int lrow=l&15, lgrp=l>>4;
  int b=wg>>5;
  int n0=(wg&31)<<7;
  v8h Ah[2][2], Al[2][2];
  #pragma unroll
  for(int T=0;T<2;T++){
    const _Float16* ph = w2h + (size_t)(wv*32 + T*16 + lrow)*64 + lgrp*8;
    const _Float16* pl = w2l + (size_t)(wv*32 + T*16 + lrow)*64 + lgrp*8;
    #pragma unroll
    for(int s=0;s<2;s++){
      Ah[T][s]=*(const v8h*)(ph+s*32);
      Al[T][s]=*(const v8h*)(pl+s*32);
    }
  }
  float bias[2][4];
  #pragma unroll
  for(int T=0;T<2;T++){
    #pragma unroll
    for(int rr=0;rr<4;rr++) bias[T][rr]=B2f[wv*32+T*16+lgrp*4+rr];
  }
  // staging: wave wv = (ks=wv>>1, pln=wv&1); stages ng=0 -> slot wv, ng=1 -> slot 4+wv
  int ks=wv>>1, pln=wv&1;
  const _Float16* src0 = (pln ? h1l : h1h)
      + (((size_t)((b<<12)+n0+lrow))<<6) + ks*32 + lgrp*8;
  const _Float16* src1 = src0 + (16<<6);

#define L2ISSUE(B_) { GLL(src0,&stage[B_][wv][0]); GLL(src1,&stage[B_][4+wv][0]); \
                      src0 += 2048; src1 += 2048; }
#define L2COMPUTE(B_,IT) { \
    _Pragma("unroll") \
    for(int ng=0;ng<2;ng++){ \
      v8h Bh[2],Bl[2]; \
      _Pragma("unroll") \
      for(int s=0;s<2;s++){ \
        Bh[s]=*(const v8h*)&stage[B_][ng*4+s*2  ][l*8]; \
        Bl[s]=*(const v8h*)&stage[B_][ng*4+s*2+1][l*8]; \
      } \
      int n=n0+(IT)*32+ng*16+lrow; \
      _Pragma("unroll") \
      for(int T=0;T<2;T++){ \
        v4f acc={bias[T][0],bias[T][1],bias[T][2],bias[T][3]}; \
        _Pragma("unroll") \
        for(int s=0;s<2;s++){ \
          acc=__builtin_amdgcn_mfma_f32_16x16x32_f16(Ah[T][s],Bh[s],acc,0,0,0); \
          acc=__builtin_amdgcn_mfma_f32_16x16x32_f16(Ah[T][s],Bl[s],acc,0,0,0); \
          acc=__builtin_amdgcn_mfma_f32_16x16x32_f16(Al[T][s],Bh[s],acc,0,0,0); \
        } \
        size_t o=(((size_t)((b<<12)+n))<<7) + wv*32 + T*16 + lgrp*4; \
        v4h sh, sl4; \
        _Pragma("unroll") \
        for(int rr=0;rr<4;rr++){ \
          float v=acc[rr]; \
          v = v>0.f ? v : 0.f; \
          _Float16 hh=(_Float16)v; \
          sh[rr]=hh; \
          sl4[rr]=(_Float16)(v-(float)hh); \
        } \
        *(v4h*)(h2h+o)=sh; \
        *(v4h*)(h2l+o)=sl4; \
      } \
    } }

  L2ISSUE(0);
  __syncthreads();
  L2ISSUE(1); L2COMPUTE(0,0); __syncthreads();
  L2ISSUE(0); L2COMPUTE(1,1); __syncthreads();
  L2ISSUE(1); L2COMPUTE(0,2); __syncthreads();
              L2COMPUTE(1,3);
#undef L2ISSUE
#undef L2COMPUTE
}

// ---------- stats of h2: half-split (grid 512), contiguous channel blocks ----------
__global__ void k_stats2(const _Float16* __restrict__ h2h, const _Float16* __restrict__ h2l,
                         float* __restrict__ partM, float* __restrict__ partMu){
  __shared__ __align__(16) float tl[64][132];
  int t=threadIdx.x, wg=blockIdx.x;     // grid 512: chunk=wg>>1, half=wg&1
  int chunk=wg>>1, half=wg&1;
  int s0=chunk*256;
  int b=s0>>12, n0=s0&4095;
  int ti=t&15, tj=t>>4;
  float acc[4][8];
  #pragma unroll
  for(int i=0;i<4;i++){
    #pragma unroll
    for(int j=0;j<8;j++) acc[i][j]=0.f;
  }
  float mu=0.f;
  for(int tile=0; tile<4; tile++){
    int nb=n0+tile*64;
    __syncthreads();
    {
      int nr=t>>2, cq=(t&3)<<5;
      const _Float16* ph = h2h + ((size_t)((b<<12)+nb+nr))*128 + cq;
      const _Float16* pl = h2l + ((size_t)((b<<12)+nb+nr))*128 + cq;
      #pragma unroll
      for(int q=0;q<4;q++){
        v8h hh=*(const v8h*)(ph+q*8);
        v8h ll=*(const v8h*)(pl+q*8);
        float4 v0=make_float4((float)hh[0]+(float)ll[0],(float)hh[1]+(float)ll[1],
                              (float)hh[2]+(float)ll[2],(float)hh[3]+(float)ll[3]);
        float4 v1=make_float4((float)hh[4]+(float)ll[4],(float)hh[5]+(float)ll[5],
                              (float)hh[6]+(float)ll[6],(float)hh[7]+(float)ll[7]);
        *(float4*)&tl[nr][cq+q*8]   = v0;
        *(float4*)&tl[nr][cq+q*8+4] = v1;
      }
    }
    __syncthreads();
    for(int k=0;k<64;k++){
      float4 av=*(const float4*)&tl[k][half*64+ti*4];
      float4 b0=*(const float4*)&tl[k][tj*8];
      float4 b1=*(const float4*)&tl[k][tj*8+4];
      float a[4]={av.x,av.y,av.z,av.w};
      float bb[8]={b0.x,b0.y,b0.z,b0.w,b1.x,b1.y,b1.z,b1.w};
      #pragma unroll
      for(int i=0;i<4;i++){
        #pragma unroll
        for(int j=0;j<8;j++) acc[i][j]=fmaf(a[i],bb[j],acc[i][j]);
      }
    }
    if(t<64){
      float s=0.f;
      for(int k=0;k<64;k++) s+=tl[k][half*64+t];
      mu+=s;
    }
  }
  #pragma unroll
  for(int i=0;i<4;i++){
    #pragma unroll
    for(int j=0;j<8;j++)
      partM[(size_t)chunk*16384+(half*64+ti*4+i)*128+(tj*8+j)]=acc[i][j];
  }
  if(t<64) partMu[chunk*128+half*64+t]=mu;
}

__global__ void k_reduceM2(const float* __restrict__ partM, const float* __restrict__ partMu,
                           float* __restrict__ M2n, float* __restrict__ mu2){
  int e=blockIdx.x*256+threadIdx.x;
  double a=0.0;
  for(int s=0;s<256;s++) a+=(double)partM[(size_t)s*16384+e];
  M2n[e]=(float)(a/65536.0);
  if(e<128){
    double m=0.0;
    for(int s=0;s<256;s++) m+=(double)partMu[s*128+e];
    mu2[e]=(float)(m/65536.0);
  }
}

// ---------- fold layer3: f16 hi/lo weight planes ----------
__global__ void k_fold3(const float* __restrict__ w3, const float* __restrict__ b3,
                        const float* __restrict__ g3, const float* __restrict__ be3,
                        const float* __restrict__ M2n, const float* __restrict__ mu2,
                        _Float16* __restrict__ w3h, _Float16* __restrict__ w3l,
                        float* __restrict__ B3f){
  int f=blockIdx.x, t=threadIdx.x;
  __shared__ float w[128];
  __shared__ double rv[2], rm[2];
  w[t]=w3[f*128+t];
  __syncthreads();
  double tm=0.0;
  for(int c=0;c<128;c++) tm += (double)w[c]*(double)M2n[c*128+t];
  double pv=tm*(double)w[t];
  double pm=(double)w[t]*(double)mu2[t];
  #pragma unroll
  for(int off=32;off>0;off>>=1){
    pv+=__shfl_xor(pv,off,64);
    pm+=__shfl_xor(pm,off,64);
  }
  if((t&63)==0){ rv[t>>6]=pv; rm[t>>6]=pm; }
  __syncthreads();
  double pmt=rm[0]+rm[1];
  double var=(rv[0]+rv[1]) - pmt*pmt;
  double m=pmt + (double)b3[f];
  double sc=(double)g3[f]/sqrt(var+(double)EPSF);
  float Wf=(float)((double)w[t]*sc);
  _Float16 hh=(_Float16)Wf;
  w3h[f*128+t]=hh;
  w3l[f*128+t]=(_Float16)(Wf-(float)hh);
  if(t==0) B3f[f]=(float)(((double)b3[f]-m)*sc+(double)be3[f]);
}

// ---------- layer3 MFMA GEMM fused with histogram (transposed C, R13-proven) ----------
__global__ __launch_bounds__(256,4) void k_gemm3_hist(
    const _Float16* __restrict__ h2h, const _Float16* __restrict__ h2l,
    const _Float16* __restrict__ w3h, const _Float16* __restrict__ w3l,
    const float* __restrict__ B3f, unsigned int* __restrict__ hist){
  __shared__ __align__(16) _Float16 stage[2][8][512];
  __shared__ unsigned int lh[4480];
  int t=threadIdx.x, wg=blockIdx.x;
  int wv=t>>6, l=t&63;
  int lrow=l&15, lgrp=l>>4;
  int b=wg>>6;
  int r=wg&63;
  int f0=(r>>3)<<7;
  int sl=r&7;
  int base=70*((b<<10)+f0);
  for(int i=t;i<4480;i+=256) lh[i]=0u;

  v8h Ah[2][4], Al[2][4];
  #pragma unroll
  for(int T=0;T<2;T++){
    const _Float16* ph = w3h + (size_t)(f0 + wv*32 + T*16 + lrow)*128 + lgrp*8;
    const _Float16* pl = w3l + (size_t)(f0 + wv*32 + T*16 + lrow)*128 + lgrp*8;
    #pragma unroll
    for(int s=0;s<4;s++){
      Ah[T][s]=*(const v8h*)(ph+s*32);
      Al[T][s]=*(const v8h*)(pl+s*32);
    }
  }
  float biasL[2]; int base70L[2];
  #pragma unroll
  for(int T=0;T<2;T++){
    int fl_=wv*32+T*16+lrow;
    biasL[T]=B3f[f0+fl_];
    base70L[T]=fl_*70;
  }
  const float wbin=(10.0f-(-10.0f))/70.0f;
  const float inv_w=1.0f/wbin;
  const float off_w=10.0f*inv_w;

  const _Float16* pH = h2h + ((size_t)((b<<12)+sl*512+lrow))*128 + wv*32 + lgrp*8;
  const _Float16* pL = h2l + ((size_t)((b<<12)+sl*512+lrow))*128 + wv*32 + lgrp*8;

#define ISSUE(B_) { GLL(pH,&stage[B_][wv*2][0]); GLL(pL,&stage[B_][wv*2+1][0]); \
                    pH+=2048; pL+=2048; }
#define COMPUTE(B_) { \
    v4f acc0={biasL[0],biasL[0],biasL[0],biasL[0]}; \
    v4f acc1={biasL[1],biasL[1],biasL[1],biasL[1]}; \
    _Pragma("unroll") \
    for(int s=0;s<4;s++){ \
      v8h Bh=*(const v8h*)&stage[B_][s*2  ][l*8]; \
      v8h Bl=*(const v8h*)&stage[B_][s*2+1][l*8]; \
      acc0=__builtin_amdgcn_mfma_f32_16x16x32_f16(Bh,Ah[0][s],acc0,0,0,0); \
      acc0=__builtin_amdgcn_mfma_f32_16x16x32_f16(Bl,Ah[0][s],acc0,0,0,0); \
      acc0=__builtin_amdgcn_mfma_f32_16x16x32_f16(Bh,Al[0][s],acc0,0,0,0); \
      acc1=__builtin_amdgcn_mfma_f32_16x16x32_f16(Bh,Ah[1][s],acc1,0,0,0); \
      acc1=__builtin_amdgcn_mfma_f32_16x16x32_f16(Bl,Ah[1][s],acc1,0,0,0); \
      acc1=__builtin_amdgcn_mfma_f32_16x16x32_f16(Bh,Al[1][s],acc1,0,0,0); \
    } \
    _Pragma("unroll") \
    for(int T=0;T<2;T++){ \
      v4f accT = T ? acc1 : acc0; \
      _Pragma("unroll") \
      for(int rr=0;rr<4;rr++){ \
        float q=fmaf(accT[rr],inv_w,off_w); \
        int bin=(int)floorf(q); \
        int loc=base70L[T]+bin; \
        if((unsigned)loc<8960u){ \
          atomicAdd(&lh[loc>>1], 1u<<((loc&1)<<4)); \
        }else{ \
          int g=base+loc; \
          if(g>=0 && g<TOTBINS) atomicAdd(&hist[g],1u); \
        } \
      } \
    } }

  ISSUE(0);
  __syncthreads();
  for(int ii=0;ii<16;ii++){
    ISSUE(1);
    COMPUTE(0);
    __syncthreads();
    if(ii<15) ISSUE(0);
    COMPUTE(1);
    __syncthreads();
  }
#undef ISSUE
#undef COMPUTE
  for(int i=t;i<4480;i+=256){
    unsigned int c=lh[i];
    if(c&0xFFFFu) atomicAdd(&hist[base+2*i],   c&0xFFFFu);
    if(c>>16)     atomicAdd(&hist[base+2*i+1], c>>16);
  }
}

__global__ void k_argmax(const unsigned int* __restrict__ hist, float* __restrict__ out){
  int g = blockIdx.x*256 + threadIdx.x;
  const unsigned int* h = hist + (size_t)g*70;
  unsigned int best=h[0]; int arg=0;
  for(int k=1;k<70;k++){
    unsigned int c=h[k];
    if(c>best){ best=c; arg=k; }
  }
  out[g]=(float)arg;
}

extern "C" void kernel_launch(void* const* d_in, const int* in_sizes, int n_in,
                              void* d_out, int out_size, void* d_ws, size_t ws_size,
                              hipStream_t stream){
  const float* x  =(const float*)d_in[0];
  const float* w1 =(const float*)d_in[1];
  const float* b1 =(const float*)d_in[2];
  const float* g1 =(const float*)d_in[3];
  const float* be1=(const float*)d_in[4];
  const float* w2 =(const float*)d_in[5];
  const float* b2 =(const float*)d_in[6];
  const float* g2 =(const float*)d_in[7];
  const float* be2=(const float*)d_in[8];
  const float* w3 =(const float*)d_in[9];
  const float* b3 =(const float*)d_in[10];
  const float* g3 =(const float*)d_in[11];
  const float* be3=(const float*)d_in[12];

  float* ws=(float*)d_ws;
  unsigned int* hist=(unsigned int*)ws;
  float* partX = ws+OFF_PARTX;
  float* W1f   = ws+OFF_W1F;
  float* B1f   = ws+OFF_B1F;
  float* M1n   = ws+OFF_M1N;
  float* mu1   = ws+OFF_MU1;
  _Float16* w2h=(_Float16*)(ws+OFF_W2H);
  _Float16* w2l=(_Float16*)(ws+OFF_W2L);
  float* B2f   = ws+OFF_B2F;
  float* pMu2  = ws+OFF_PMU2;
  float* M2n   = ws+OFF_M2N;
  float* mu2   = ws+OFF_MU2;
  _Float16* w3h=(_Float16*)(ws+OFF_W3H);
  _Float16* w3l=(_Float16*)(ws+OFF_W3L);
  float* B3f   = ws+OFF_B3F;
  _Float16* h1h=(_Float16*)(ws+OFF_H1H);
  _Float16* h1l=(_Float16*)(ws+OFF_H1L);
  _Float16* h2h=(_Float16*)(ws+OFF_H2H);
  _Float16* h2l=(_Float16*)(ws+OFF_H2L);
  float* partM1=(float*)(ws+OFF_H2H);             // 512*4096 = 2.10M floats (h2 scratch)
  float* pMu1  =(float*)(ws+OFF_H2H+2200000);     // 512*64 floats, still in h2 scratch
  float* partM2=(float*)(ws+OFF_H1H);             // h1 region free after layer2

  hipMemsetAsync(hist, 0, (size_t)TOTBINS*sizeof(unsigned int), stream);

  k_statsX  <<<256,256,0,stream>>>(x, partX);
  k_fold1   <<<1,  256,0,stream>>>(partX,w1,b1,g1,be1,W1f,B1f);
  k_l1s1    <<<512,256,0,stream>>>(x,W1f,B1f,h1h,h1l,partM1,pMu1);
  k_reduceM1<<<16, 256,0,stream>>>(partM1,pMu1,M1n,mu1);
  k_fold2   <<<128, 64,0,stream>>>(w2,b2,g2,be2,M1n,mu1,w2h,w2l,B2f);
  k_layer2  <<<512,256,0,stream>>>(h1h,h1l,w2h,w2l,B2f,h2h,h2l);
  k_stats2  <<<512,256,0,stream>>>(h2h,h2l,partM2,pMu2);
  k_reduceM2<<<64, 256,0,stream>>>(partM2,pMu2,M2n,mu2);
  k_fold3   <<<1024,128,0,stream>>>(w3,b3,g3,be3,M2n,mu2,w3h,w3l,B3f);
  k_gemm3_hist<<<1024,256,0,stream>>>(h2h,h2l,w3h,w3l,B3f,hist);
  k_argmax  <<<64, 256,0,stream>>>(hist,(float*)d_out);
}

// Round 17
// 202.406 us; speedup vs baseline: 1.0543x; 1.0543x over previous
//
#include <hip/hip_runtime.h>

#define EPSF 1e-5f
#define TOTBINS 1146880   // 70*16*1024

typedef _Float16 v8h __attribute__((ext_vector_type(8)));
typedef _Float16 v4h __attribute__((ext_vector_type(4)));
typedef float v4f __attribute__((ext_vector_type(4)));

// ---- workspace offsets (in float slots) ----
#define OFF_PARTX   1146880
#define OFF_W1F     1149952
#define OFF_B1F     1150144
#define OFF_PMU1    1150208
#define OFF_M1N     1166592
#define OFF_MU1     1170688
#define OFF_W2H     1170752
#define OFF_W2L     1174848
#define OFF_B2F     1178944
#define OFF_PMU2    1179072
#define OFF_M2N     1211840
#define OFF_MU2     1228224
#define OFF_W3H     1228352   // 1024x128 f16 = 65536 float slots
#define OFF_W3L     1293888
#define OFF_B3F     1359424
#define OFF_H1H     1360448   // 16*4096*64 f16 = 2097152 float slots
#define OFF_H1L     3457600
#define OFF_H2H     5554752   // 16*4096*128 f16 = 4194304 float slots
#define OFF_H2L     9749056   // ends 13943360 (55.8 MB)

#define GLL(src,dst) __builtin_amdgcn_global_load_lds( \
    (const __attribute__((address_space(1))) void*)(src), \
    (__attribute__((address_space(3))) void*)(dst), 16, 0, 0)

// ---------- stats of x ----------
__global__ void k_statsX(const float* __restrict__ x, float* __restrict__ part){
  __shared__ float red[12][256];
  int t = threadIdx.x;
  int s = blockIdx.x*256 + t;
  int b = s >> 12, n = s & 4095;
  const float* xb = x + (size_t)b*12288 + n;
  float x0 = xb[0], x1 = xb[4096], x2 = xb[8192];
  float v[12] = {x0,x1,x2, x0*x0,x0*x1,x0*x2, x1*x1,x1*x2,x2*x2, 0.f,0.f,0.f};
  #pragma unroll
  for(int j=0;j<12;j++) red[j][t]=v[j];
  __syncthreads();
  for(int off=128; off>0; off>>=1){
    if(t<off){
      #pragma unroll
      for(int j=0;j<12;j++) red[j][t]+=red[j][t+off];
    }
    __syncthreads();
  }
  if(t<12) part[blockIdx.x*12+t]=red[t][0];
}

__global__ void k_fold1(const float* __restrict__ part,
                        const float* __restrict__ w1, const float* __restrict__ b1,
                        const float* __restrict__ g1, const float* __restrict__ be1,
                        float* __restrict__ W1f, float* __restrict__ B1f){
  __shared__ double S[12];
  int t=threadIdx.x;
  if(t<12){
    double a=0.0;
    for(int s=0;s<256;s++) a+=(double)part[s*12+t];
    S[t]=a;
  }
  __syncthreads();
  if(t<64){
    double inv = 1.0/65536.0;
    double mu[3]={S[0]*inv,S[1]*inv,S[2]*inv};
    double M[3][3];
    M[0][0]=S[3]*inv; M[0][1]=S[4]*inv; M[0][2]=S[5]*inv;
    M[1][1]=S[6]*inv; M[1][2]=S[7]*inv; M[2][2]=S[8]*inv;
    M[1][0]=M[0][1]; M[2][0]=M[0][2]; M[2][1]=M[1][2];
    double w[3]={(double)w1[t*3],(double)w1[t*3+1],(double)w1[t*3+2]};
    double wm=0.0, q=0.0;
    for(int c=0;c<3;c++){
      wm += w[c]*mu[c];
      for(int d=0;d<3;d++) q += w[c]*w[d]*M[c][d];
    }
    double var = q - wm*wm;
    double m = wm + (double)b1[t];
    double sc = (double)g1[t] / sqrt(var + (double)EPSF);
    for(int c=0;c<3;c++) W1f[t*3+c]=(float)(w[c]*sc);
    B1f[t]=(float)(((double)b1[t]-m)*sc + (double)be1[t]);
  }
}

// ---------- fused layer1 + stats1 (R14-proven) ----------
__global__ void k_l1s1(const float* __restrict__ x, const float* __restrict__ W1f,
                       const float* __restrict__ B1f,
                       _Float16* __restrict__ h1h, _Float16* __restrict__ h1l,
                       float* __restrict__ partM, float* __restrict__ partMu){
  __shared__ __align__(16) float tl[64][68];
  __shared__ float Wls[192];
  __shared__ float Bls[64];
  int t=threadIdx.x, wg=blockIdx.x;
  int s0=wg*256;
  int b=s0>>12, n0=s0&4095;
  int ti=t&15, tj=t>>4;
  if(t<192) Wls[t]=W1f[t];
  if(t<64)  Bls[t]=B1f[t];
  float acc[4][4];
  #pragma unroll
  for(int i=0;i<4;i++){
    #pragma unroll
    for(int j=0;j<4;j++) acc[i][j]=0.f;
  }
  float mu=0.f;
  for(int tile=0; tile<4; tile++){
    int nb=n0+tile*64;
    __syncthreads();
    {
      int nr=t>>2, cq=(t&3)<<4;
      int n=nb+nr;
      const float* xb = x + (size_t)b*12288 + n;
      float x0=xb[0], x1=xb[4096], x2=xb[8192];
      size_t off = ((size_t)((b<<12)+n))<<6;
      #pragma unroll
      for(int q=0;q<2;q++){
        v8h vh, vl;
        float4 r0, r1;
        #pragma unroll
        for(int e=0;e<8;e++){
          int f=cq+q*8+e;
          float v = fmaf(Wls[f*3+2],x2, fmaf(Wls[f*3+1],x1, fmaf(Wls[f*3],x0, Bls[f])));
          v = v>0.f ? v : 0.f;
          _Float16 hh=(_Float16)v;
          _Float16 ll=(_Float16)(v-(float)hh);
          vh[e]=hh; vl[e]=ll;
          float rec=(float)hh+(float)ll;
          if(e<4) ((float*)&r0)[e]=rec; else ((float*)&r1)[e-4]=rec;
        }
        *(v8h*)(h1h+off+cq+q*8)=vh;
        *(v8h*)(h1l+off+cq+q*8)=vl;
        *(float4*)&tl[nr][cq+q*8]   = r0;
        *(float4*)&tl[nr][cq+q*8+4] = r1;
      }
    }
    __syncthreads();
    for(int k=0;k<64;k++){
      float4 av = *(const float4*)&tl[k][ti*4];
      float4 bv = *(const float4*)&tl[k][tj*4];
      float a[4]={av.x,av.y,av.z,av.w};
      float bb[4]={bv.x,bv.y,bv.z,bv.w};
      #pragma unroll
      for(int i=0;i<4;i++){
        #pragma unroll
        for(int j=0;j<4;j++) acc[i][j]=fmaf(a[i],bb[j],acc[i][j]);
      }
    }
    if(t<64){
      float ss=0.f;
      for(int k=0;k<64;k++) ss+=tl[k][t];
      mu+=ss;
    }
  }
  #pragma unroll
  for(int i=0;i<4;i++){
    #pragma unroll
    for(int j=0;j<4;j++)
      partM[(size_t)wg*4096+(ti*4+i)*64+(tj*4+j)]=acc[i][j];
  }
  if(t<64) partMu[wg*64+t]=mu;
}

__global__ void k_reduceM1(const float* __restrict__ partM, const float* __restrict__ partMu,
                           float* __restrict__ M1n, float* __restrict__ mu1){
  int e=blockIdx.x*256+threadIdx.x;
  double a=0.0;
  for(int s=0;s<256;s++) a+=(double)partM[(size_t)s*4096+e];
  M1n[e]=(float)(a/65536.0);
  if(e<64){
    double m=0.0;
    for(int s=0;s<256;s++) m+=(double)partMu[s*64+e];
    mu1[e]=(float)(m/65536.0);
  }
}

// ---------- fold layer2: f16 hi/lo weight planes ----------
__global__ void k_fold2(const float* __restrict__ w2, const float* __restrict__ b2,
                        const float* __restrict__ g2, const float* __restrict__ be2,
                        const float* __restrict__ M1n, const float* __restrict__ mu1,
                        _Float16* __restrict__ w2h, _Float16* __restrict__ w2l,
                        float* __restrict__ B2f){
  int f=blockIdx.x, t=threadIdx.x;   // block=64
  __shared__ float w[64];
  w[t]=w2[f*64+t];
  __syncthreads();
  double tm=0.0;
  for(int c=0;c<64;c++) tm += (double)w[c]*(double)M1n[c*64+t];
  double pv=tm*(double)w[t];
  double pm=(double)w[t]*(double)mu1[t];
  #pragma unroll
  for(int off=32;off>0;off>>=1){
    pv+=__shfl_xor(pv,off,64);
    pm+=__shfl_xor(pm,off,64);
  }
  double var=pv-pm*pm;
  double m=pm+(double)b2[f];
  double sc=(double)g2[f]/sqrt(var+(double)EPSF);
  float Wf=(float)((double)w[t]*sc);
  _Float16 hh=(_Float16)Wf;
  w2h[f*64+t]=hh;
  w2l[f*64+t]=(_Float16)(Wf-(float)hh);
  if(t==0) B2f[f]=(float)(((double)b2[f]-m)*sc+(double)be2[f]);
}

// ---------- layer2 MFMA GEMM: 128f x 128n per WG, dbuf, 1 barrier/iter ----------
// grid 512 = 16b x 32 nslice(128n); 4 waves x 32f (two 16f tiles); 8 iters of 16n.
__global__ __launch_bounds__(256,4) void k_layer2(
    const _Float16* __restrict__ h1h, const _Float16* __restrict__ h1l,
    const _Float16* __restrict__ w2h, const _Float16* __restrict__ w2l,
    const float* __restrict__ B2f,
    _Float16* __restrict__ h2h, _Float16* __restrict__ h2l){
  __shared__ __align__(16) _Float16 stage[2][4][512];  // [buf][ks*2+plane][slot*8]
  int t=threadIdx.x, wg=blockIdx.x;
  int wv=t>>6, l=t&63;
  int lrow=l&15, lgrp=l>>4;
  int b=wg>>5;
  int n0=(wg&31)<<7;
  v8h Ah[2][2], Al[2][2];
  #pragma unroll
  for(int T=0;T<2;T++){
    const _Float16* ph = w2h + (size_t)(wv*32 + T*16 + lrow)*64 + lgrp*8;
    const _Float16* pl = w2l + (size_t)(wv*32 + T*16 + lrow)*64 + lgrp*8;
    #pragma unroll
    for(int s=0;s<2;s++){
      Ah[T][s]=*(const v8h*)(ph+s*32);
      Al[T][s]=*(const v8h*)(pl+s*32);
    }
  }
  float bias[2][4];
  #pragma unroll
  for(int T=0;T<2;T++){
    #pragma unroll
    for(int rr=0;rr<4;rr++) bias[T][rr]=B2f[wv*32+T*16+lgrp*4+rr];
  }
  int ks=wv>>1, pln=wv&1;
  const _Float16* src = (pln ? h1l : h1h)
      + (((size_t)((b<<12)+n0+lrow))<<6) + ks*32 + lgrp*8;

#define L2ISSUE(B_) { GLL(src,&stage[B_][wv][0]); src += 1024; }
#define L2COMPUTE(B_,IT) { \
    v8h Bh[2],Bl[2]; \
    _Pragma("unroll") \
    for(int s=0;s<2;s++){ \
      Bh[s]=*(const v8h*)&stage[B_][s*2  ][l*8]; \
      Bl[s]=*(const v8h*)&stage[B_][s*2+1][l*8]; \
    } \
    int n=n0+(IT)*16+lrow; \
    _Pragma("unroll") \
    for(int T=0;T<2;T++){ \
      v4f acc={bias[T][0],bias[T][1],bias[T][2],bias[T][3]}; \
      _Pragma("unroll") \
      for(int s=0;s<2;s++){ \
        acc=__builtin_amdgcn_mfma_f32_16x16x32_f16(Ah[T][s],Bh[s],acc,0,0,0); \
        acc=__builtin_amdgcn_mfma_f32_16x16x32_f16(Ah[T][s],Bl[s],acc,0,0,0); \
        acc=__builtin_amdgcn_mfma_f32_16x16x32_f16(Al[T][s],Bh[s],acc,0,0,0); \
      } \
      size_t o=(((size_t)((b<<12)+n))<<7) + wv*32 + T*16 + lgrp*4; \
      v4h sh, sl4; \
      _Pragma("unroll") \
      for(int rr=0;rr<4;rr++){ \
        float v=acc[rr]; \
        v = v>0.f ? v : 0.f; \
        _Float16 hh=(_Float16)v; \
        sh[rr]=hh; \
        sl4[rr]=(_Float16)(v-(float)hh); \
      } \
      *(v4h*)(h2h+o)=sh; \
      *(v4h*)(h2l+o)=sl4; \
    } }

  L2ISSUE(0);
  __syncthreads();
  for(int ii=0;ii<4;ii++){
    L2ISSUE(1);
    L2COMPUTE(0,2*ii);
    __syncthreads();
    if(ii<3) L2ISSUE(0);
    L2COMPUTE(1,2*ii+1);
    __syncthreads();
  }
#undef L2ISSUE
#undef L2COMPUTE
}

// ---------- stats of h2: half-split (grid 512), contiguous channel blocks ----------
__global__ void k_stats2(const _Float16* __restrict__ h2h, const _Float16* __restrict__ h2l,
                         float* __restrict__ partM, float* __restrict__ partMu){
  __shared__ __align__(16) float tl[64][132];
  int t=threadIdx.x, wg=blockIdx.x;     // grid 512: chunk=wg>>1, half=wg&1
  int chunk=wg>>1, half=wg&1;
  int s0=chunk*256;
  int b=s0>>12, n0=s0&4095;
  int ti=t&15, tj=t>>4;
  float acc[4][8];
  #pragma unroll
  for(int i=0;i<4;i++){
    #pragma unroll
    for(int j=0;j<8;j++) acc[i][j]=0.f;
  }
  float mu=0.f;
  for(int tile=0; tile<4; tile++){
    int nb=n0+tile*64;
    __syncthreads();
    {
      int nr=t>>2, cq=(t&3)<<5;
      const _Float16* ph = h2h + ((size_t)((b<<12)+nb+nr))*128 + cq;
      const _Float16* pl = h2l + ((size_t)((b<<12)+nb+nr))*128 + cq;
      #pragma unroll
      for(int q=0;q<4;q++){
        v8h hh=*(const v8h*)(ph+q*8);
        v8h ll=*(const v8h*)(pl+q*8);
        float4 v0=make_float4((float)hh[0]+(float)ll[0],(float)hh[1]+(float)ll[1],
                              (float)hh[2]+(float)ll[2],(float)hh[3]+(float)ll[3]);
        float4 v1=make_float4((float)hh[4]+(float)ll[4],(float)hh[5]+(float)ll[5],
                              (float)hh[6]+(float)ll[6],(float)hh[7]+(float)ll[7]);
        *(float4*)&tl[nr][cq+q*8]   = v0;
        *(float4*)&tl[nr][cq+q*8+4] = v1;
      }
    }
    __syncthreads();
    for(int k=0;k<64;k++){
      float4 av=*(const float4*)&tl[k][half*64+ti*4];   // ci = half*64+ti*4+i
      float4 b0=*(const float4*)&tl[k][tj*8];           // cj = tj*8+j : broadcast
      float4 b1=*(const float4*)&tl[k][tj*8+4];
      float a[4]={av.x,av.y,av.z,av.w};
      float bb[8]={b0.x,b0.y,b0.z,b0.w,b1.x,b1.y,b1.z,b1.w};
      #pragma unroll
      for(int i=0;i<4;i++){
        #pragma unroll
        for(int j=0;j<8;j++) acc[i][j]=fmaf(a[i],bb[j],acc[i][j]);
      }
    }
    if(t<64){
      float s=0.f;
      for(int k=0;k<64;k++) s+=tl[k][half*64+t];
      mu+=s;
    }
  }
  #pragma unroll
  for(int i=0;i<4;i++){
    #pragma unroll
    for(int j=0;j<8;j++)
      partM[(size_t)chunk*16384+(half*64+ti*4+i)*128+(tj*8+j)]=acc[i][j];
  }
  if(t<64) partMu[chunk*128+half*64+t]=mu;
}

__global__ void k_reduceM2(const float* __restrict__ partM, const float* __restrict__ partMu,
                           float* __restrict__ M2n, float* __restrict__ mu2){
  int e=blockIdx.x*256+threadIdx.x;
  double a=0.0;
  for(int s=0;s<256;s++) a+=(double)partM[(size_t)s*16384+e];
  M2n[e]=(float)(a/65536.0);
  if(e<128){
    double m=0.0;
    for(int s=0;s<256;s++) m+=(double)partMu[s*128+e];
    mu2[e]=(float)(m/65536.0);
  }
}

// ---------- fold layer3: f16 hi/lo weight planes ----------
__global__ void k_fold3(const float* __restrict__ w3, const float* __restrict__ b3,
                        const float* __restrict__ g3, const float* __restrict__ be3,
                        const float* __restrict__ M2n, const float* __restrict__ mu2,
                        _Float16* __restrict__ w3h, _Float16* __restrict__ w3l,
                        float* __restrict__ B3f){
  int f=blockIdx.x, t=threadIdx.x;
  __shared__ float w[128];
  __shared__ double rv[2], rm[2];
  w[t]=w3[f*128+t];
  __syncthreads();
  double tm=0.0;
  for(int c=0;c<128;c++) tm += (double)w[c]*(double)M2n[c*128+t];
  double pv=tm*(double)w[t];
  double pm=(double)w[t]*(double)mu2[t];
  #pragma unroll
  for(int off=32;off>0;off>>=1){
    pv+=__shfl_xor(pv,off,64);
    pm+=__shfl_xor(pm,off,64);
  }
  if((t&63)==0){ rv[t>>6]=pv; rm[t>>6]=pm; }
  __syncthreads();
  double pmt=rm[0]+rm[1];
  double var=(rv[0]+rv[1]) - pmt*pmt;
  double m=pmt + (double)b3[f];
  double sc=(double)g3[f]/sqrt(var+(double)EPSF);
  float Wf=(float)((double)w[t]*sc);
  _Float16 hh=(_Float16)Wf;
  w3h[f*128+t]=hh;
  w3l[f*128+t]=(_Float16)(Wf-(float)hh);
  if(t==0) B3f[f]=(float)(((double)b3[f]-m)*sc+(double)be3[f]);
}

// ---------- layer3 MFMA GEMM fused with histogram (transposed C, R13-proven) ----------
__global__ __launch_bounds__(256,4) void k_gemm3_hist(
    const _Float16* __restrict__ h2h, const _Float16* __restrict__ h2l,
    const _Float16* __restrict__ w3h, const _Float16* __restrict__ w3l,
    const float* __restrict__ B3f, unsigned int* __restrict__ hist){
  __shared__ __align__(16) _Float16 stage[2][8][512];
  __shared__ unsigned int lh[4480];
  int t=threadIdx.x, wg=blockIdx.x;
  int wv=t>>6, l=t&63;
  int lrow=l&15, lgrp=l>>4;
  int b=wg>>6;
  int r=wg&63;
  int f0=(r>>3)<<7;
  int sl=r&7;
  int base=70*((b<<10)+f0);
  for(int i=t;i<4480;i+=256) lh[i]=0u;

  v8h Ah[2][4], Al[2][4];
  #pragma unroll
  for(int T=0;T<2;T++){
    const _Float16* ph = w3h + (size_t)(f0 + wv*32 + T*16 + lrow)*128 + lgrp*8;
    const _Float16* pl = w3l + (size_t)(f0 + wv*32 + T*16 + lrow)*128 + lgrp*8;
    #pragma unroll
    for(int s=0;s<4;s++){
      Ah[T][s]=*(const v8h*)(ph+s*32);
      Al[T][s]=*(const v8h*)(pl+s*32);
    }
  }
  float biasL[2]; int base70L[2];
  #pragma unroll
  for(int T=0;T<2;T++){
    int fl_=wv*32+T*16+lrow;
    biasL[T]=B3f[f0+fl_];
    base70L[T]=fl_*70;
  }
  const float wbin=(10.0f-(-10.0f))/70.0f;
  const float inv_w=1.0f/wbin;
  const float off_w=10.0f*inv_w;

  const _Float16* pH = h2h + ((size_t)((b<<12)+sl*512+lrow))*128 + wv*32 + lgrp*8;
  const _Float16* pL = h2l + ((size_t)((b<<12)+sl*512+lrow))*128 + wv*32 + lgrp*8;

#define ISSUE(B_) { GLL(pH,&stage[B_][wv*2][0]); GLL(pL,&stage[B_][wv*2+1][0]); \
                    pH+=2048; pL+=2048; }
#define COMPUTE(B_) { \
    v4f acc0={biasL[0],biasL[0],biasL[0],biasL[0]}; \
    v4f acc1={biasL[1],biasL[1],biasL[1],biasL[1]}; \
    _Pragma("unroll") \
    for(int s=0;s<4;s++){ \
      v8h Bh=*(const v8h*)&stage[B_][s*2  ][l*8]; \
      v8h Bl=*(const v8h*)&stage[B_][s*2+1][l*8]; \
      acc0=__builtin_amdgcn_mfma_f32_16x16x32_f16(Bh,Ah[0][s],acc0,0,0,0); \
      acc0=__builtin_amdgcn_mfma_f32_16x16x32_f16(Bl,Ah[0][s],acc0,0,0,0); \
      acc0=__builtin_amdgcn_mfma_f32_16x16x32_f16(Bh,Al[0][s],acc0,0,0,0); \
      acc1=__builtin_amdgcn_mfma_f32_16x16x32_f16(Bh,Ah[1][s],acc1,0,0,0); \
      acc1=__builtin_amdgcn_mfma_f32_16x16x32_f16(Bl,Ah[1][s],acc1,0,0,0); \
      acc1=__builtin_amdgcn_mfma_f32_16x16x32_f16(Bh,Al[1][s],acc1,0,0,0); \
    } \
    _Pragma("unroll") \
    for(int T=0;T<2;T++){ \
      v4f accT = T ? acc1 : acc0; \
      _Pragma("unroll") \
      for(int rr=0;rr<4;rr++){ \
        float q=fmaf(accT[rr],inv_w,off_w); \
        int bin=(int)floorf(q); \
        int loc=base70L[T]+bin; \
        if((unsigned)loc<8960u){ \
          atomicAdd(&lh[loc>>1], 1u<<((loc&1)<<4)); \
        }else{ \
          int g=base+loc; \
          if(g>=0 && g<TOTBINS) atomicAdd(&hist[g],1u); \
        } \
      } \
    } }

  ISSUE(0);
  __syncthreads();
  for(int ii=0;ii<16;ii++){
    ISSUE(1);
    COMPUTE(0);
    __syncthreads();
    if(ii<15) ISSUE(0);
    COMPUTE(1);
    __syncthreads();
  }
#undef ISSUE
#undef COMPUTE
  for(int i=t;i<4480;i+=256){
    unsigned int c=lh[i];
    if(c&0xFFFFu) atomicAdd(&hist[base+2*i],   c&0xFFFFu);
    if(c>>16)     atomicAdd(&hist[base+2*i+1], c>>16);
  }
}

__global__ void k_argmax(const unsigned int* __restrict__ hist, float* __restrict__ out){
  int g = blockIdx.x*256 + threadIdx.x;
  const unsigned int* h = hist + (size_t)g*70;
  unsigned int best=h[0]; int arg=0;
  for(int k=1;k<70;k++){
    unsigned int c=h[k];
    if(c>best){ best=c; arg=k; }
  }
  out[g]=(float)arg;
}

extern "C" void kernel_launch(void* const* d_in, const int* in_sizes, int n_in,
                              void* d_out, int out_size, void* d_ws, size_t ws_size,
                              hipStream_t stream){
  const float* x  =(const float*)d_in[0];
  const float* w1 =(const float*)d_in[1];
  const float* b1 =(const float*)d_in[2];
  const float* g1 =(const float*)d_in[3];
  const float* be1=(const float*)d_in[4];
  const float* w2 =(const float*)d_in[5];
  const float* b2 =(const float*)d_in[6];
  const float* g2 =(const float*)d_in[7];
  const float* be2=(const float*)d_in[8];
  const float* w3 =(const float*)d_in[9];
  const float* b3 =(const float*)d_in[10];
  const float* g3 =(const float*)d_in[11];
  const float* be3=(const float*)d_in[12];

  float* ws=(float*)d_ws;
  unsigned int* hist=(unsigned int*)ws;
  float* partX = ws+OFF_PARTX;
  float* W1f   = ws+OFF_W1F;
  float* B1f   = ws+OFF_B1F;
  float* pMu1  = ws+OFF_PMU1;
  float* M1n   = ws+OFF_M1N;
  float* mu1   = ws+OFF_MU1;
  _Float16* w2h=(_Float16*)(ws+OFF_W2H);
  _Float16* w2l=(_Float16*)(ws+OFF_W2L);
  float* B2f   = ws+OFF_B2F;
  float* pMu2  = ws+OFF_PMU2;
  float* M2n   = ws+OFF_M2N;
  float* mu2   = ws+OFF_MU2;
  _Float16* w3h=(_Float16*)(ws+OFF_W3H);
  _Float16* w3l=(_Float16*)(ws+OFF_W3L);
  float* B3f   = ws+OFF_B3F;
  _Float16* h1h=(_Float16*)(ws+OFF_H1H);
  _Float16* h1l=(_Float16*)(ws+OFF_H1L);
  _Float16* h2h=(_Float16*)(ws+OFF_H2H);
  _Float16* h2l=(_Float16*)(ws+OFF_H2L);
  float* partM1=(float*)(ws+OFF_H2H);   // h2 region free until k_layer2
  float* partM2=(float*)(ws+OFF_H1H);   // h1 region free after k_layer2

  hipMemsetAsync(hist, 0, (size_t)TOTBINS*sizeof(unsigned int), stream);

  k_statsX  <<<256,256,0,stream>>>(x, partX);
  k_fold1   <<<1,  256,0,stream>>>(partX,w1,b1,g1,be1,W1f,B1f);
  k_l1s1    <<<256,256,0,stream>>>(x,W1f,B1f,h1h,h1l,partM1,pMu1);
  k_reduceM1<<<16, 256,0,stream>>>(partM1,pMu1,M1n,mu1);
  k_fold2   <<<128, 64,0,stream>>>(w2,b2,g2,be2,M1n,mu1,w2h,w2l,B2f);
  k_layer2  <<<512,256,0,stream>>>(h1h,h1l,w2h,w2l,B2f,h2h,h2l);
  k_stats2  <<<512,256,0,stream>>>(h2h,h2l,partM2,pMu2);
  k_reduceM2<<<64, 256,0,stream>>>(partM2,pMu2,M2n,mu2);
  k_fold3   <<<1024,128,0,stream>>>(w3,b3,g3,be3,M2n,mu2,w3h,w3l,B3f);
  k_gemm3_hist<<<1024,256,0,stream>>>(h2h,h2l,w3h,w3l,B3f,hist);
  k_argmax  <<<64, 256,0,stream>>>(hist,(float*)d_out);
}